// Round 8
// baseline (372.911 us; speedup 1.0000x reference)
//
#include <hip/hip_runtime.h>
#include <hip/hip_bf16.h>
#include <stdint.h>

#define T_STEPS 16
#define BATCH   16
#define CHANNELS 32
#define HGT 128
#define WID 128
#define HW (HGT*WID)      // 16384
#define KSEL 8192         // ascending 0-based rank of threshold = N - k
#define CAP 1024          // candidate buffer (safety)
#define SMALL 128         // stop narrowing when candidate set <= SMALL
#define NB 4096           // histogram bins
#define NBS 1024.0f       // initial scale: 4096 bins over [0,4)

typedef float vfloat4 __attribute__((ext_vector_type(4)));
typedef float vfloat2 __attribute__((ext_vector_type(2)));

__device__ __forceinline__ vfloat4 v4max(vfloat4 a, vfloat4 b) {
    vfloat4 r;
    r.x = fmaxf(a.x, b.x); r.y = fmaxf(a.y, b.y);
    r.z = fmaxf(a.z, b.z); r.w = fmaxf(a.w, b.w);
    return r;
}

__device__ __forceinline__ uint32_t wave_incl_scan(uint32_t v, int lane) {
    #pragma unroll
    for (int off = 1; off < 64; off <<= 1) {
        uint32_t u = __shfl_up(v, off, 64);
        if (lane >= off) v += u;
    }
    return v;
}

// LDS-only barrier: drain DS ops, do NOT drain vmcnt (keeps global prefetch
// loads in flight across the barrier — __syncthreads would drain them).
__device__ __forceinline__ void lds_barrier() {
    asm volatile("s_waitcnt lgkmcnt(0)" ::: "memory");
    __builtin_amdgcn_s_barrier();
}

// ---------- kernel 1: channel max pool (unchanged from round 7) ----------
__global__ __launch_bounds__(256)
void pool_max_kernel(const float* __restrict__ x, float* __restrict__ pooled) {
    int tid  = blockIdx.x * blockDim.x + threadIdx.x;   // 1,048,576 threads
    int base = tid * 4;
    int tb   = base >> 14;              // /HW
    int pix  = base & (HW - 1);
    const vfloat4* src = (const vfloat4*)(x + (size_t)tb * CHANNELS * HW + pix);
    vfloat4 a0 = src[0 * (HW/4)];
    vfloat4 a1 = src[1 * (HW/4)];
    vfloat4 a2 = src[2 * (HW/4)];
    vfloat4 a3 = src[3 * (HW/4)];
    #pragma unroll
    for (int c = 4; c < CHANNELS; c += 4) {
        a0 = v4max(a0, src[(c+0) * (HW/4)]);
        a1 = v4max(a1, src[(c+1) * (HW/4)]);
        a2 = v4max(a2, src[(c+2) * (HW/4)]);
        a3 = v4max(a3, src[(c+3) * (HW/4)]);
    }
    *(vfloat4*)(pooled + base) = v4max(v4max(a0, a1), v4max(a2, a3));
}

// ---------- kernel 2: lif0 v4 — raw LDS barriers + t+1 prefetch + fold-clear ----------
__global__ __launch_bounds__(1024)
void lif0_kernel(const float* __restrict__ pooled, uint8_t* __restrict__ spk) {
    __shared__ uint32_t hist[NB];        // 16 KB
    __shared__ uint32_t s_wtot[16];
    __shared__ float    col[CAP];
    __shared__ uint32_t s_sel[4];        // jsel, r_new, cnt_new, collect-counter
    __shared__ float    s_thr;

    const int b    = blockIdx.x;
    const int tid  = threadIdx.x;
    const int wid  = tid >> 6;
    const int lane = tid & 63;

    float m[16];
    #pragma unroll
    for (int i = 0; i < 16; ++i) m[i] = 0.0f;

    // initial clear of all 4096 bins
    hist[tid] = 0; hist[tid + 1024] = 0; hist[tid + 2048] = 0; hist[tid + 3072] = 0;

    // prefetch t=0 data into registers
    const float4* p0 = (const float4*)(pooled + (size_t)b * HW);
    float4 x0 = p0[tid], x1 = p0[1024 + tid], x2 = p0[2048 + tid], x3 = p0[3072 + tid];

    lds_barrier();   // clear visible before first atomics

    for (int t = 0; t < T_STEPS; ++t) {
        // ---- integrate from prefetched registers (bit-identical to ref) ----
        m[ 0] = 0.25f * m[ 0] + x0.x;  m[ 1] = 0.25f * m[ 1] + x0.y;
        m[ 2] = 0.25f * m[ 2] + x0.z;  m[ 3] = 0.25f * m[ 3] + x0.w;
        m[ 4] = 0.25f * m[ 4] + x1.x;  m[ 5] = 0.25f * m[ 5] + x1.y;
        m[ 6] = 0.25f * m[ 6] + x1.z;  m[ 7] = 0.25f * m[ 7] + x1.w;
        m[ 8] = 0.25f * m[ 8] + x2.x;  m[ 9] = 0.25f * m[ 9] + x2.y;
        m[10] = 0.25f * m[10] + x2.z;  m[11] = 0.25f * m[11] + x2.w;
        m[12] = 0.25f * m[12] + x3.x;  m[13] = 0.25f * m[13] + x3.y;
        m[14] = 0.25f * m[14] + x3.z;  m[15] = 0.25f * m[15] + x3.w;

        // ---- issue prefetch of t+1 (overlaps the whole select phase;
        //      raw barriers don't drain vmcnt) ----
        if (t + 1 < T_STEPS) {
            const float4* pn = (const float4*)(pooled + ((size_t)(t+1) * BATCH + b) * HW);
            x0 = pn[tid]; x1 = pn[1024 + tid]; x2 = pn[2048 + tid]; x3 = pn[3072 + tid];
        }

        // ---- exact select of ascending rank KSEL ----
        float    rlo   = 0.0f;
        float    sc    = NBS;            // 4096 bins over [0,4): hot bin ~20-30
        uint32_t r     = KSEL;
        uint32_t cnt   = HW;
        uint32_t amask = 0xFFFFu;
        for (int iter = 0;; ++iter) {
            // histogram (bins are zero: initial clear or fold-clear of prev scan)
            #pragma unroll
            for (int i = 0; i < 16; ++i) {
                if (amask & (1u << i)) {
                    int bn = (int)((m[i] - rlo) * sc);
                    bn = min(max(bn, 0), NB - 1);
                    atomicAdd(&hist[bn], 1u);
                }
            }
            lds_barrier();                               // A
            // rank scan over 4 bins/thread + fold-clear
            uint4 hc = *(const uint4*)&hist[tid * 4];
            uint4 z; z.x = z.y = z.z = z.w = 0u;
            *(uint4*)&hist[tid * 4] = z;                 // fold clear (pre-C)
            uint32_t psum = hc.x + hc.y + hc.z + hc.w;
            uint32_t incl = wave_incl_scan(psum, lane);
            if (lane == 63) s_wtot[wid] = incl;
            lds_barrier();                               // B
            uint32_t wbase = 0;
            for (int w = 0; w < wid; ++w) wbase += s_wtot[w];
            uint32_t excl = wbase + incl - psum;
            if (tid == 0) s_sel[3] = 0;
            if (r >= excl && r < excl + psum) {          // exactly one thread
                uint32_t acc = excl; int dsel = -1; uint32_t nr = 0, nc = 0;
                if (r < acc + hc.x) { dsel = tid*4+0; nr = r-acc; nc = hc.x; } acc += hc.x;
                if (dsel < 0 && r < acc + hc.y) { dsel = tid*4+1; nr = r-acc; nc = hc.y; } acc += hc.y;
                if (dsel < 0 && r < acc + hc.z) { dsel = tid*4+2; nr = r-acc; nc = hc.z; } acc += hc.z;
                if (dsel < 0 && r < acc + hc.w) { dsel = tid*4+3; nr = r-acc; nc = hc.w; }
                s_sel[0] = (uint32_t)dsel; s_sel[1] = nr; s_sel[2] = nc;
            }
            lds_barrier();                               // C
            const int jsel = (int)s_sel[0];
            r = s_sel[1]; cnt = s_sel[2];
            uint32_t nm = 0;
            #pragma unroll
            for (int i = 0; i < 16; ++i) {
                if (amask & (1u << i)) {
                    int bn = (int)((m[i] - rlo) * sc);
                    bn = min(max(bn, 0), NB - 1);
                    if (bn == jsel) nm |= (1u << i);
                }
            }
            amask = nm;
            rlo += (float)jsel / sc;
            sc  *= (float)NB;
            if (cnt <= SMALL || iter >= 3) break;
        }

        // ---- collect candidates (~20-30 atomics) ----
        #pragma unroll
        for (int i = 0; i < 16; ++i) {
            if (amask & (1u << i)) {
                uint32_t u = atomicAdd(&s_sel[3], 1u);
                if (u < CAP) col[u] = m[i];
            }
        }
        lds_barrier();                                   // D
        // ---- exact rank-select among candidates ----
        {
            uint32_t ncol = min(cnt, (uint32_t)CAP);
            for (uint32_t j = tid; j < ncol; j += 1024) {
                float v = col[j];
                uint32_t less = 0, leq = 0;
                for (uint32_t i2 = 0; i2 < ncol; ++i2) {
                    float u = col[i2];
                    less += (u < v);
                    leq  += (u <= v);
                }
                if (less <= r && r < leq) s_thr = v;     // k-th largest, exact bits
            }
        }
        lds_barrier();                                   // E
        const float thr = s_thr;

        // ---- spikes + hard reset (no trailing barrier needed) ----
        uchar4* so4 = (uchar4*)(spk + ((size_t)t * BATCH + b) * HW);
        #pragma unroll
        for (int i = 0; i < 4; ++i) {
            uchar4 s4;
            s4.x = (m[i*4+0] >= thr) ? 1 : 0;
            s4.y = (m[i*4+1] >= thr) ? 1 : 0;
            s4.z = (m[i*4+2] >= thr) ? 1 : 0;
            s4.w = (m[i*4+3] >= thr) ? 1 : 0;
            if (s4.x) m[i*4+0] = 0.0f;
            if (s4.y) m[i*4+1] = 0.0f;
            if (s4.z) m[i*4+2] = 0.0f;
            if (s4.w) m[i*4+3] = 0.0f;
            so4[i * 1024 + tid] = s4;
        }
    }
}

// ---------- kernel 3: fused 7x7 conv (cross-correlation) + lif1 ----------
__global__ __launch_bounds__(256)
void conv_lif1_kernel(const uint8_t* __restrict__ spk, const float* __restrict__ wconv,
                      float* __restrict__ out_spike, float* __restrict__ out_mem) {
    __shared__ float tile[14][136];  // 8-row stripe + 3 halo each side
    const int bidx   = blockIdx.x;   // 0..255
    const int b      = bidx >> 4;
    const int stripe = bidx & 15;
    const int r0     = stripe * 8;
    const int tid    = threadIdx.x;
    const int sr     = tid >> 5;           // 0..7
    const int c0     = (tid & 31) << 2;    // 0,4,...,124

    float w[49];
    #pragma unroll
    for (int i = 0; i < 49; ++i) w[i] = wconv[i];   // uniform -> scalar regs

    float mem[4] = {0.0f, 0.0f, 0.0f, 0.0f};

    for (int t = 0; t < T_STEPS; ++t) {
        __syncthreads();   // tile reuse guard
        const uint8_t* sp = spk + ((size_t)t * BATCH + b) * HW;
        for (int k = tid; k < 14 * 134; k += 256) {
            int row  = k / 134;
            int colp = k - row * 134;
            int gr = r0 - 3 + row;
            int gc = colp - 3;
            float v = 0.0f;
            if ((unsigned)gr < HGT && (unsigned)gc < WID)
                v = (float)sp[gr * WID + gc];
            tile[row][colp] = v;
        }
        __syncthreads();
        float a0 = 0.f, a1 = 0.f, a2 = 0.f, a3 = 0.f;
        #pragma unroll
        for (int dy = 0; dy < 7; ++dy) {
            const float* rowp = &tile[sr + dy][c0];
            vfloat4 u = *(const vfloat4*)rowp;
            vfloat4 v = *(const vfloat4*)(rowp + 4);
            vfloat2 e = *(const vfloat2*)(rowp + 8);
            float r[10] = {u.x,u.y,u.z,u.w, v.x,v.y,v.z,v.w, e.x,e.y};
            #pragma unroll
            for (int dx = 0; dx < 7; ++dx) {
                float wv = w[dy * 7 + dx];
                a0 = fmaf(r[dx + 0], wv, a0);
                a1 = fmaf(r[dx + 1], wv, a1);
                a2 = fmaf(r[dx + 2], wv, a2);
                a3 = fmaf(r[dx + 3], wv, a3);
            }
        }
        float m0 = 0.25f * mem[0] + a0;
        float m1 = 0.25f * mem[1] + a1;
        float m2 = 0.25f * mem[2] + a2;
        float m3 = 0.25f * mem[3] + a3;
        float s0 = (m0 > 1.0f) ? 1.0f : 0.0f;
        float s1 = (m1 > 1.0f) ? 1.0f : 0.0f;
        float s2 = (m2 > 1.0f) ? 1.0f : 0.0f;
        float s3 = (m3 > 1.0f) ? 1.0f : 0.0f;
        size_t o = (((size_t)t * BATCH + b) << 14) + (size_t)(r0 + sr) * WID + c0;
        vfloat4 sv = {s0, s1, s2, s3};
        vfloat4 mv = {m0, m1, m2, m3};
        *(vfloat4*)(out_spike + o) = sv;
        *(vfloat4*)(out_mem   + o) = mv;
        mem[0] = m0 - s0; mem[1] = m1 - s1; mem[2] = m2 - s2; mem[3] = m3 - s3;
    }
}

extern "C" void kernel_launch(void* const* d_in, const int* in_sizes, int n_in,
                              void* d_out, int out_size, void* d_ws, size_t ws_size,
                              hipStream_t stream) {
    const float* x     = (const float*)d_in[0];
    const float* wconv = (const float*)d_in[1];
    float* out = (float*)d_out;

    const size_t n_pooled = (size_t)T_STEPS * BATCH * HW;     // 4,194,304
    float*   pooled = (float*)d_ws;
    uint8_t* spk    = (uint8_t*)d_ws + n_pooled * sizeof(float);

    // TIMING INSTRUMENT: pool launched TWICE (idempotent). Round 9 drops the
    // dup with identical binaries -> P = dur8 - dur9 exactly.
    pool_max_kernel<<<4096, 256, 0, stream>>>(x, pooled);
    pool_max_kernel<<<4096, 256, 0, stream>>>(x, pooled);
    lif0_kernel<<<BATCH, 1024, 0, stream>>>(pooled, spk);
    conv_lif1_kernel<<<256, 256, 0, stream>>>(spk, wconv, out, out + n_pooled);
}